// Round 6
// baseline (479.167 us; speedup 1.0000x reference)
//
#include <hip/hip_runtime.h>
#include <math.h>

namespace {
constexpr int BB = 8;
constexpr int CH = 256;
constexpr int CQ = 32;
constexpr int NN = 4096;
}

typedef float f32x4 __attribute__((ext_vector_type(4)));
typedef short bf16x8 __attribute__((ext_vector_type(8)));
typedef unsigned short us8 __attribute__((ext_vector_type(8)));

#define MFMA16(a, b, c) __builtin_amdgcn_mfma_f32_16x16x32_bf16(a, b, c, 0, 0, 0)
#define LOG2E 1.4426950408889634f

__device__ __forceinline__ unsigned short f2bf(float x) {
    unsigned int u = __float_as_uint(x);
    u += 0x7fffu + ((u >> 16) & 1u);
    return (unsigned short)(u >> 16);
}
__device__ __forceinline__ float bf2f(unsigned short h) {
    return __uint_as_float(((unsigned int)h) << 16);
}
__device__ __forceinline__ void gload16(const void* g, void* l) {
    __builtin_amdgcn_global_load_lds(
        (const __attribute__((address_space(1))) unsigned int*)g,
        (__attribute__((address_space(3))) unsigned int*)l, 16, 0, 0);
}

// ---------------------------------------------------------------------------
// Kernel 0: split W (wq|wk|wv concat, 320x256) into bf16 hi/lo.
// ---------------------------------------------------------------------------
__global__ __launch_bounds__(256) void wsplit_kernel(
    const float* __restrict__ wq, const float* __restrict__ wk,
    const float* __restrict__ wv,
    unsigned short* __restrict__ wh, unsigned short* __restrict__ wl)
{
    int idx = blockIdx.x * 256 + threadIdx.x;   // 0..81919
    float v;
    if (idx < 8192)       v = wq[idx];
    else if (idx < 16384) v = wk[idx - 8192];
    else                  v = wv[idx - 16384];
    unsigned short hi = f2bf(v);
    wh[idx] = hi;
    wl[idx] = f2bf(v - bf2f(hi));
}

// ---------------------------------------------------------------------------
// Kernel 1: transpose+split X [b][256c][4096n] fp32 -> Xh/Xl [b][n][256c] bf16.
// ---------------------------------------------------------------------------
__global__ __launch_bounds__(256) void transpose_kernel(
    const float* __restrict__ x,
    unsigned short* __restrict__ xh, unsigned short* __restrict__ xl)
{
    __shared__ float xf[64 * 68];                 // fp32 tile, padded rows
    __shared__ unsigned short hs[64 * 80];        // bf16 [n][64c] padded
    __shared__ unsigned short ls[64 * 80];
    const int t  = threadIdx.x;
    const int b  = blockIdx.x >> 8;
    const int tl = blockIdx.x & 255;
    const int c0 = (tl >> 6) * 64;
    const int n0 = (tl & 63) * 64;

    #pragma unroll
    for (int i = 0; i < 4; ++i) {
        int idx = i * 256 + t;
        int c = idx >> 4, nf = idx & 15;
        float4 v4 = *(const float4*)(x + ((size_t)(b * 256 + c0 + c)) * NN + n0 + nf * 4);
        *(float4*)(xf + c * 68 + nf * 4) = v4;
    }
    __syncthreads();

    const int n = t & 63;
    #pragma unroll
    for (int loop = 0; loop < 2; ++loop) {
        int chunk = (t >> 6) + 4 * loop;          // 0..7 (8 c's each)
        us8 h8, l8;
        #pragma unroll
        for (int j = 0; j < 8; ++j) {
            float v = xf[(chunk * 8 + j) * 68 + n];
            unsigned short hi = f2bf(v);
            h8[j] = hi;
            l8[j] = f2bf(v - bf2f(hi));
        }
        *(us8*)(hs + n * 80 + chunk * 8) = h8;
        *(us8*)(ls + n * 80 + chunk * 8) = l8;
    }
    __syncthreads();

    {
        int rn = t >> 2, piece = t & 3;
        size_t grow = ((size_t)(b * NN + n0 + rn)) * 256 + c0 + piece * 16;
        *(us8*)(xh + grow)     = *(const us8*)(hs + rn * 80 + piece * 16);
        *(us8*)(xh + grow + 8) = *(const us8*)(hs + rn * 80 + piece * 16 + 8);
        *(us8*)(xl + grow)     = *(const us8*)(ls + rn * 80 + piece * 16);
        *(us8*)(xl + grow + 8) = *(const us8*)(ls + rn * 80 + piece * 16 + 8);
    }
}

// ---------------------------------------------------------------------------
// Kernel 2: proj GEMM via MFMA (unchanged from round 4; Q pre-scaled log2e).
// ---------------------------------------------------------------------------
#define PJ_XL 32768
#define PJ_VE 16384
__global__ __launch_bounds__(256, 2) void proj_kernel(
    const unsigned short* __restrict__ xh, const unsigned short* __restrict__ xl,
    const unsigned short* __restrict__ wh, const unsigned short* __restrict__ wl,
    const float* __restrict__ bq, const float* __restrict__ bk,
    const float* __restrict__ bv,
    unsigned short* __restrict__ qh, unsigned short* __restrict__ ql,
    unsigned short* __restrict__ kh, unsigned short* __restrict__ kl,
    unsigned short* __restrict__ vt)
{
    __shared__ __align__(16) unsigned char smem[65536];
    const int t    = threadIdx.x;
    const int lane = t & 63;
    const int w    = t >> 6;
    const int l16  = lane & 15;
    const int quad = lane >> 4;
    const int b    = blockIdx.x >> 6;
    const int n0   = (blockIdx.x & 63) << 6;

    const unsigned char* xhB = (const unsigned char*)(xh + ((size_t)b * NN + n0) * 256);
    const unsigned char* xlB = (const unsigned char*)(xl + ((size_t)b * NN + n0) * 256);
    #pragma unroll
    for (int j = 0; j < 8; ++j) {
        int idx = j * 256 + t;
        int r = idx >> 5, cl = idx & 31;
        int cg = cl ^ (r & 7);
        gload16(xhB + (size_t)r * 512 + cg * 16, smem + idx * 16);
        gload16(xlB + (size_t)r * 512 + cg * 16, smem + PJ_XL + idx * 16);
    }
    __syncthreads();

    f32x4 acc[5][4] = {};
    #pragma unroll 1
    for (int kc = 0; kc < 8; ++kc) {
        bf16x8 ah[5], al[5];
        #pragma unroll
        for (int i = 0; i < 5; ++i) {
            int och = (w * 5 + i) * 16 + l16;
            ah[i] = *(const bf16x8*)(wh + och * 256 + kc * 32 + quad * 8);
            al[i] = *(const bf16x8*)(wl + och * 256 + kc * 32 + quad * 8);
        }
        #pragma unroll
        for (int nt = 0; nt < 4; ++nt) {
            int roff = (nt * 16 + l16) * 512 + (((kc * 4 + quad) ^ (l16 & 7)) * 16);
            bf16x8 bh = *(const bf16x8*)(smem + roff);
            bf16x8 bl = *(const bf16x8*)(smem + PJ_XL + roff);
            #pragma unroll
            for (int i = 0; i < 5; ++i) {
                acc[i][nt] = MFMA16(ah[i], bh, acc[i][nt]);
                acc[i][nt] = MFMA16(al[i], bh, acc[i][nt]);
                acc[i][nt] = MFMA16(ah[i], bl, acc[i][nt]);
            }
        }
    }
    __syncthreads();

    #pragma unroll
    for (int i = 0; i < 5; ++i) {
        int tile = w * 5 + i;
        if (tile < 4) {
            #pragma unroll
            for (int r = 0; r < 4; ++r) {
                int och = tile * 16 + quad * 4 + r;
                float bias = (och < 32) ? bq[och] : bk[och - 32];
                int arr = (och < 32) ? 0 : 2;
                int oq = och & 31;
                #pragma unroll
                for (int nt = 0; nt < 4; ++nt) {
                    float val = acc[i][nt][r] + bias;
                    if (och < 32) val *= LOG2E;
                    unsigned short hi = f2bf(val);
                    unsigned short lo = f2bf(val - bf2f(hi));
                    *(unsigned short*)(smem + arr * 4096 + (nt * 16 + l16) * 64 + oq * 2) = hi;
                    *(unsigned short*)(smem + (arr + 1) * 4096 + (nt * 16 + l16) * 64 + oq * 2) = lo;
                }
            }
        } else {
            #pragma unroll
            for (int r = 0; r < 4; ++r) {
                int voch = tile * 16 + quad * 4 + r - 64;
                float bias = bv[voch];
                #pragma unroll
                for (int nt = 0; nt < 4; ++nt) {
                    *(unsigned short*)(smem + PJ_VE + voch * 136 + (nt * 16 + l16) * 2)
                        = f2bf(acc[i][nt][r] + bias);
                }
            }
        }
    }
    __syncthreads();

    {
        unsigned short* dsts[4] = { qh, ql, kh, kl };
        int arr = t >> 6, n = t & 63;
        unsigned short* dst = dsts[arr] + ((size_t)b * NN + n0 + n) * 32;
        #pragma unroll
        for (int i = 0; i < 4; ++i)
            *(us8*)(dst + i * 8) = *(const us8*)(smem + arr * 4096 + n * 64 + i * 16);
    }
    #pragma unroll
    for (int p = 0; p < 4; ++p) {
        int voch = p * 64 + (t >> 2), piece = t & 3;
        unsigned short* dst = vt + ((size_t)b * CH + voch) * NN + n0 + piece * 16;
        *(us8*)(dst)     = *(const us8*)(smem + PJ_VE + voch * 136 + piece * 32);
        *(us8*)(dst + 8) = *(const us8*)(smem + PJ_VE + voch * 136 + piece * 32 + 16);
    }
}

// ---------------------------------------------------------------------------
// Kernel 3a: key-split flash attention. Grid 1024 = (batch&7 = XCD) x 64
// q-tiles x 2 key-halves. Block: 4 waves, 64 queries, 2048 keys (32 tiles).
// LDS 40KB (V single 32KB + P single 8KB) -> 4 blocks/CU -> 4 waves/SIMD.
// Per-XCD L2 traffic unchanged vs round 4 (each block reads K/2 + V/2).
// No softmax max => partials are exactly additive; block writes raw fp32
// O-partial (64KB) + S-partial (64 floats); combine_kernel finishes.
// Two barriers/tile: E -> A(P+V ready) -> Kpf + PV -> B -> V-stage(t+1).
// ---------------------------------------------------------------------------
#define A_V  0          // V: 256ch x 128B = 32 KB
#define A_P  32768      // P: 64 rows x 128B = 8 KB (aliased by SM post-loop)

__global__ __launch_bounds__(256, 4) void attn_split_kernel(
    const unsigned short* __restrict__ qh, const unsigned short* __restrict__ ql,
    const unsigned short* __restrict__ kh, const unsigned short* __restrict__ kl,
    const unsigned short* __restrict__ vt,
    float* __restrict__ PO, float* __restrict__ SP)
{
    __shared__ __align__(16) unsigned char smem[40960];
    const int t    = threadIdx.x;
    const int lane = t & 63;
    const int w    = t >> 6;
    const int l16  = lane & 15;
    const int quad = lane >> 4;
    const int b    = blockIdx.x & 7;
    const int qi   = blockIdx.x >> 3;        // 0..127
    const int qtile = qi & 63;
    const int half  = qi >> 6;               // key half 0/1
    const int n0   = qtile << 6;

    // Q B-frags (hi/lo); Q pre-scaled by log2e
    bf16x8 qhA[4], qlA[4];
    #pragma unroll
    for (int qt = 0; qt < 4; ++qt) {
        size_t row = (size_t)b * NN + n0 + qt * 16 + l16;
        qhA[qt] = *(const bf16x8*)(qh + row * 32 + quad * 8);
        qlA[qt] = *(const bf16x8*)(ql + row * 32 + quad * 8);
    }

    // K A-frag base: wave w owns keys w*16..+15 of each 64-key tile in half
    const unsigned short* khbase =
        kh + ((size_t)b * NN + half * 2048 + w * 16 + l16) * 32 + quad * 8;
    const unsigned short* klbase =
        kl + ((size_t)b * NN + half * 2048 + w * 16 + l16) * 32 + quad * 8;
    const unsigned char* vtB = (const unsigned char*)(vt + (size_t)b * CH * NN);

    // hoisted V-stage offsets (256 rows x 128B per tile, chunk-XOR swizzle)
    unsigned int voff[8];
    #pragma unroll
    for (int j = 0; j < 8; ++j) {
        int idx = j * 256 + t;
        int r = idx >> 3, cl = idx & 7;
        int cg = cl ^ (r & 7);
        voff[j] = (unsigned int)(r * 8192 + cg * 16);
    }
    const unsigned char* vcur = vtB + half * 4096;   // +128 B per tile

    // P-write offset (lane-constant)
    const int poff = l16 * 128 + ((((w << 1) | (quad >> 1)) ^ (l16 & 7)) << 4)
                   + ((quad & 1) << 3);

    f32x4 acc[4][4] = {};
    float S[4] = {};

    // prologue: K(0) regs, then stage V(0)
    bf16x8 kch = *(const bf16x8*)(khbase);
    bf16x8 kcl = *(const bf16x8*)(klbase);
    #pragma unroll
    for (int j = 0; j < 8; ++j)
        gload16(vcur + voff[j], smem + A_V + (j * 256 + t) * 16);

    unsigned char* P = smem + A_P;
    #pragma unroll 1
    for (int tile = 0; tile < 32; ++tile) {
        // ---- E: swapped operands; lane holds 4 keys (quad*4+r) x query l16 ----
        #pragma unroll
        for (int qt = 0; qt < 4; ++qt) {
            f32x4 e = { 0.f, 0.f, 0.f, 0.f };
            e = MFMA16(kch, qhA[qt], e);
            e = MFMA16(kch, qlA[qt], e);
            e = MFMA16(kcl, qhA[qt], e);
            float p0 = exp2f(e[0]), p1 = exp2f(e[1]);
            float p2 = exp2f(e[2]), p3 = exp2f(e[3]);
            unsigned int u01, u23;
            asm("v_cvt_pk_bf16_f32 %0, %1, %2" : "=v"(u01) : "v"(p0), "v"(p1));
            asm("v_cvt_pk_bf16_f32 %0, %1, %2" : "=v"(u23) : "v"(p2), "v"(p3));
            S[qt] += (__uint_as_float(u01 << 16) + __uint_as_float(u01 & 0xffff0000u))
                   + (__uint_as_float(u23 << 16) + __uint_as_float(u23 & 0xffff0000u));
            int2 pk2 = { (int)u01, (int)u23 };
            *(int2*)(P + qt * 2048 + poff) = pk2;
        }

        __syncthreads();   // A: P(t) visible; V(t) stage drained

        // ---- K(t+1) prefetch (regs; latency covered by PV) ----
        const int m1 = ((tile + 1) & 31) * 64;
        bf16x8 knh = *(const bf16x8*)(khbase + (size_t)m1 * 32);
        bf16x8 knl = *(const bf16x8*)(klbase + (size_t)m1 * 32);

        // ---- PV: A = P rows (queries), B = V rows (wave's 64 channels) ----
        #pragma unroll
        for (int ks = 0; ks < 2; ++ks) {
            bf16x8 af[4], bfr[4];
            #pragma unroll
            for (int qt = 0; qt < 4; ++qt) {
                int row = qt * 16 + l16;
                af[qt] = *(const bf16x8*)(P + row * 128
                                            + (((ks * 4 + quad) ^ (l16 & 7)) << 4));
            }
            #pragma unroll
            for (int ct = 0; ct < 4; ++ct) {
                int vrow = w * 64 + ct * 16 + l16;
                bfr[ct] = *(const bf16x8*)(smem + A_V + vrow * 128
                                              + (((ks * 4 + quad) ^ (l16 & 7)) << 4));
            }
            __builtin_amdgcn_s_setprio(1);
            #pragma unroll
            for (int qt = 0; qt < 4; ++qt)
                #pragma unroll
                for (int ct = 0; ct < 4; ++ct)
                    acc[qt][ct] = MFMA16(af[qt], bfr[ct], acc[qt][ct]);
            __builtin_amdgcn_s_setprio(0);
        }

        __syncthreads();   // B: all PV reads of P and V done

        // ---- issue V-stage(t+1) into the single V buffer ----
        if (tile < 31) {
            vcur += 128;
            #pragma unroll
            for (int j = 0; j < 8; ++j)
                gload16(vcur + voff[j], smem + A_V + (j * 256 + t) * 16);
        }
        kch = knh;
        kcl = knl;
    }

    // S: reduce over quads, then across waves via LDS (aliases P, dead now)
    #pragma unroll
    for (int mask = 16; mask <= 32; mask <<= 1)
        #pragma unroll
        for (int qt = 0; qt < 4; ++qt)
            S[qt] += __shfl_xor(S[qt], mask);
    float* SM = (float*)(smem + A_P);
    if (quad == 0) {
        #pragma unroll
        for (int qt = 0; qt < 4; ++qt)
            SM[w * 64 + qt * 16 + l16] = S[qt];
    }
    __syncthreads();

    const size_t pidx = (size_t)((half * 8 + b) * 64 + qtile);
    if (t < 64)
        SP[pidx * 64 + t] = SM[t] + SM[64 + t] + SM[128 + t] + SM[192 + t];

    float* POb = PO + pidx * 16384;
    #pragma unroll
    for (int qt = 0; qt < 4; ++qt)
        #pragma unroll
        for (int ct = 0; ct < 4; ++ct)
            *(f32x4*)(POb + (size_t)(w * 64 + ct * 16 + l16) * 64
                          + qt * 16 + quad * 4) = acc[qt][ct];
}

// ---------------------------------------------------------------------------
// Kernel 3b: combine halves: out = floor(g1*(O0+O1)/(S0+S1)*256)/256.
// Grid 512 = (b&7) x 64 q-tiles; 256 threads = 16 c-rows x 16 q-pieces.
// ---------------------------------------------------------------------------
__global__ __launch_bounds__(256) void combine_kernel(
    const float* __restrict__ PO, const float* __restrict__ SP,
    const float* __restrict__ gptr, float* __restrict__ out)
{
    const int t = threadIdx.x;
    const int b = blockIdx.x & 7;
    const int qtile = blockIdx.x >> 3;
    const float g1 = 1.f + gptr[0];
    const int q4 = t & 15, cr = t >> 4;

    const size_t i0 = (size_t)((0 * 8 + b) * 64 + qtile);
    const size_t i1 = (size_t)((1 * 8 + b) * 64 + qtile);
    float4 s0 = *(const float4*)(SP + i0 * 64 + q4 * 4);
    float4 s1 = *(const float4*)(SP + i1 * 64 + q4 * 4);
    const float is0 = g1 / (s0.x + s1.x);
    const float is1 = g1 / (s0.y + s1.y);
    const float is2 = g1 / (s0.z + s1.z);
    const float is3 = g1 / (s0.w + s1.w);

    const float* p0 = PO + i0 * 16384;
    const float* p1 = PO + i1 * 16384;
    float* ob = out + (size_t)b * CH * NN + qtile * 64;
    #pragma unroll
    for (int cc = 0; cc < 16; ++cc) {
        int c = cc * 16 + cr;
        float4 a = *(const float4*)(p0 + c * 64 + q4 * 4);
        float4 d = *(const float4*)(p1 + c * 64 + q4 * 4);
        float4 o;
        o.x = floorf((a.x + d.x) * is0 * 256.f) * 0.00390625f;
        o.y = floorf((a.y + d.y) * is1 * 256.f) * 0.00390625f;
        o.z = floorf((a.z + d.z) * is2 * 256.f) * 0.00390625f;
        o.w = floorf((a.w + d.w) * is3 * 256.f) * 0.00390625f;
        *(float4*)(ob + (size_t)c * NN + q4 * 4) = o;
    }
}

// ---------------------------------------------------------------------------
// Kernel 3-fallback: round-4 attention (proven 128.7 us) if ws too small.
// ---------------------------------------------------------------------------
#define FB_P0 0
#define FB_P1 8192
#define FB_V0 16384
#define FB_V1 49152
#define FB_SM 16384

__global__ __launch_bounds__(256, 2) void attn_fb_kernel(
    const unsigned short* __restrict__ qh, const unsigned short* __restrict__ ql,
    const unsigned short* __restrict__ kh, const unsigned short* __restrict__ kl,
    const unsigned short* __restrict__ vt, const float* __restrict__ gptr,
    float* __restrict__ out)
{
    __shared__ __align__(16) unsigned char smem[81920];
    const int t    = threadIdx.x;
    const int lane = t & 63;
    const int w    = t >> 6;
    const int l16  = lane & 15;
    const int quad = lane >> 4;
    const int b    = blockIdx.x & 7;
    const int n0   = (blockIdx.x >> 3) << 6;

    bf16x8 qhA[4], qlA[4];
    #pragma unroll
    for (int qt = 0; qt < 4; ++qt) {
        size_t row = (size_t)b * NN + n0 + qt * 16 + l16;
        qhA[qt] = *(const bf16x8*)(qh + row * 32 + quad * 8);
        qlA[qt] = *(const bf16x8*)(ql + row * 32 + quad * 8);
    }

    const unsigned short* khbase = kh + ((size_t)b * NN + w * 16 + l16) * 32 + quad * 8;
    const unsigned short* klbase = kl + ((size_t)b * NN + w * 16 + l16) * 32 + quad * 8;
    const unsigned char*  vtB    = (const unsigned char*)(vt + (size_t)b * CH * NN);

    const unsigned char* vsrc[8];
    int vlds[8];
    #pragma unroll
    for (int j = 0; j < 8; ++j) {
        int idx = j * 256 + t;
        int r = idx >> 3, cl = idx & 7;
        int cg = cl ^ (r & 7);
        vsrc[j] = vtB + (size_t)r * 8192 + cg * 16;
        vlds[j] = idx * 16;
    }
    const int poff = l16 * 128 + ((((w << 1) | (quad >> 1)) ^ (l16 & 7)) << 4)
                   + ((quad & 1) << 3);

    f32x4 acc[4][4] = {};
    float S[4] = {};

    bf16x8 kch = *(const bf16x8*)(khbase);
    bf16x8 kcl = *(const bf16x8*)(klbase);
    #pragma unroll
    for (int j = 0; j < 8; ++j)
        gload16(vsrc[j], smem + FB_V0 + vlds[j]);

    #pragma unroll 1
    for (int tile = 0; tile < 64; ++tile) {
        unsigned char* P = smem + ((tile & 1) ? FB_P1 : FB_P0);
        #pragma unroll
        for (int qt = 0; qt < 4; ++qt) {
            f32x4 e = { 0.f, 0.f, 0.f, 0.f };
            e = MFMA16(kch, qhA[qt], e);
            e = MFMA16(kch, qlA[qt], e);
            e = MFMA16(kcl, qhA[qt], e);
            float p0 = exp2f(e[0]), p1 = exp2f(e[1]);
            float p2 = exp2f(e[2]), p3 = exp2f(e[3]);
            unsigned int u01, u23;
            asm("v_cvt_pk_bf16_f32 %0, %1, %2" : "=v"(u01) : "v"(p0), "v"(p1));
            asm("v_cvt_pk_bf16_f32 %0, %1, %2" : "=v"(u23) : "v"(p2), "v"(p3));
            S[qt] += (__uint_as_float(u01 << 16) + __uint_as_float(u01 & 0xffff0000u))
                   + (__uint_as_float(u23 << 16) + __uint_as_float(u23 & 0xffff0000u));
            int2 pk2 = { (int)u01, (int)u23 };
            *(int2*)(P + qt * 2048 + poff) = pk2;
        }

        __syncthreads();

        const int m1 = ((tile + 1) & 63) * 64;
        bf16x8 knh = *(const bf16x8*)(khbase + (size_t)m1 * 32);
        bf16x8 knl = *(const bf16x8*)(klbase + (size_t)m1 * 32);
        if (tile < 63) {
            unsigned char* vdst = smem + ((tile & 1) ? FB_V0 : FB_V1);
            #pragma unroll
            for (int j = 0; j < 8; ++j) {
                vsrc[j] += 128;
                gload16(vsrc[j], vdst + vlds[j]);
            }
        }

        const unsigned char* VB = smem + ((tile & 1) ? FB_V1 : FB_V0);
        #pragma unroll
        for (int ks = 0; ks < 2; ++ks) {
            bf16x8 af[4], bfr[4];
            #pragma unroll
            for (int qt = 0; qt < 4; ++qt) {
                int row = qt * 16 + l16;
                af[qt] = *(const bf16x8*)(P + row * 128
                                            + (((ks * 4 + quad) ^ (l16 & 7)) << 4));
            }
            #pragma unroll
            for (int ct = 0; ct < 4; ++ct) {
                int vrow = w * 64 + ct * 16 + l16;
                bfr[ct] = *(const bf16x8*)(VB + vrow * 128
                                              + (((ks * 4 + quad) ^ (l16 & 7)) << 4));
            }
            __builtin_amdgcn_s_setprio(1);
            #pragma unroll
            for (int qt = 0; qt < 4; ++qt)
                #pragma unroll
                for (int ct = 0; ct < 4; ++ct)
                    acc[qt][ct] = MFMA16(af[qt], bfr[ct], acc[qt][ct]);
            __builtin_amdgcn_s_setprio(0);
        }
        kch = knh;
        kcl = knl;
    }

    #pragma unroll
    for (int mask = 16; mask <= 32; mask <<= 1)
        #pragma unroll
        for (int qt = 0; qt < 4; ++qt)
            S[qt] += __shfl_xor(S[qt], mask);
    float* SM = (float*)(smem + FB_SM);
    if (quad == 0) {
        #pragma unroll
        for (int qt = 0; qt < 4; ++qt)
            SM[w * 64 + qt * 16 + l16] = S[qt];
    }
    __syncthreads();

    const float g1 = 1.f + gptr[0];
    float* ob = out + (size_t)b * CH * NN;
    #pragma unroll
    for (int qt = 0; qt < 4; ++qt) {
        float is[4];
        #pragma unroll
        for (int r = 0; r < 4; ++r) {
            int qi = qt * 16 + quad * 4 + r;
            float Sf = SM[qi] + SM[64 + qi] + SM[128 + qi] + SM[192 + qi];
            is[r] = g1 / Sf;
        }
        #pragma unroll
        for (int ct = 0; ct < 4; ++ct) {
            float4 o4;
            o4.x = floorf(acc[qt][ct][0] * is[0] * 256.f) * 0.00390625f;
            o4.y = floorf(acc[qt][ct][1] * is[1] * 256.f) * 0.00390625f;
            o4.z = floorf(acc[qt][ct][2] * is[2] * 256.f) * 0.00390625f;
            o4.w = floorf(acc[qt][ct][3] * is[3] * 256.f) * 0.00390625f;
            *(float4*)(ob + (size_t)(w * 64 + ct * 16 + l16) * NN
                          + n0 + qt * 16 + quad * 4) = o4;
        }
    }
}

// ---------------------------------------------------------------------------
extern "C" void kernel_launch(void* const* d_in, const int* in_sizes, int n_in,
                              void* d_out, int out_size, void* d_ws, size_t ws_size,
                              hipStream_t stream) {
    const float* x  = (const float*)d_in[0];
    const float* wq = (const float*)d_in[1];
    const float* bq = (const float*)d_in[2];
    const float* wk = (const float*)d_in[3];
    const float* bk = (const float*)d_in[4];
    const float* wv = (const float*)d_in[5];
    const float* bv = (const float*)d_in[6];
    const float* gm = (const float*)d_in[7];
    float* out = (float*)d_out;

    // Layout (shorts): persistent-into-attn arrays first, then proj-only
    // inputs (xh/xl/wh/wl) which PO may alias after proj completes.
    unsigned short* ws = (unsigned short*)d_ws;
    const size_t XSZ = (size_t)BB * NN * 256;   // 8,388,608
    const size_t WSZ = 320 * 256;               // 81,920
    const size_t QSZ = (size_t)BB * NN * 32;    // 1,048,576
    unsigned short* qh = ws;
    unsigned short* ql = qh + QSZ;
    unsigned short* kh = ql + QSZ;
    unsigned short* kl = kh + QSZ;
    unsigned short* vt = kl + QSZ;
    unsigned short* xh = vt + XSZ;              // proj-only region starts here
    unsigned short* xl = xh + XSZ;
    unsigned short* wh = xl + XSZ;
    unsigned short* wl = wh + WSZ;

    const size_t po_off  = (size_t)(4 * QSZ + XSZ) * 2;     // bytes: 25,165,824
    const size_t po_sz   = (size_t)1024 * 16384 * 4;        // 67,108,864
    const size_t sp_sz   = (size_t)1024 * 64 * 4;           // 262,144
    float* PO = (float*)((char*)d_ws + po_off);             // aliases xh/xl/wh/wl
    float* SP = (float*)((char*)d_ws + po_off + po_sz);
    const size_t need = po_off + po_sz + sp_sz;             // 92,536,832

    wsplit_kernel<<<320, 256, 0, stream>>>(wq, wk, wv, wh, wl);
    transpose_kernel<<<2048, 256, 0, stream>>>(x, xh, xl);
    proj_kernel<<<512, 256, 0, stream>>>(xh, xl, wh, wl, bq, bk, bv,
                                         qh, ql, kh, kl, vt);
    if (ws_size >= need) {
        attn_split_kernel<<<1024, 256, 0, stream>>>(qh, ql, kh, kl, vt, PO, SP);
        combine_kernel<<<512, 256, 0, stream>>>(PO, SP, gm, out);
    } else {
        attn_fb_kernel<<<512, 256, 0, stream>>>(qh, ql, kh, kl, vt, gm, out);
    }
}